// Round 2
// 920.415 us; speedup vs baseline: 1.1436x; 1.1436x over previous
//
#include <hip/hip_runtime.h>
#include <hip/hip_bf16.h>
#include <stdint.h>

#define NUM_H 8
#define DIM 16
#define HD 128
#define IN_F 256
#define E_F 64
#define NEG_SLOPE 0.2f
#define NB 8  // nodes per block in k_out

#define NCT 24    // col-tiles: 3 matrices * 128 cols / 16
#define KSTEPS 8  // 256 / 32
#define WELEMS (KSTEPS * NCT * 64 * 8)  // 98304 bf16 elems per W plane (192 KB)

typedef __bf16 bf16x8 __attribute__((ext_vector_type(8)));
typedef float f32x4 __attribute__((ext_vector_type(4)));

__device__ __forceinline__ float b2f(__hip_bfloat16 x) { return __bfloat162float(x); }
__device__ __forceinline__ __hip_bfloat16 f2b(float x) { return __float2bfloat16(x); }

// ---------------- zero int array (deg) ----------------
__global__ void k_zero_int(int* p, int n) {
    int i = blockIdx.x * blockDim.x + threadIdx.x;
    int stride = gridDim.x * blockDim.x;
    for (; i < n; i += stride) p[i] = 0;
}

// ---------------- CSR build: histogram of targets ----------------
__global__ void k_hist(const int* __restrict__ eidx, int* __restrict__ deg, int n_edges) {
    int e = blockIdx.x * blockDim.x + threadIdx.x;
    if (e < n_edges) atomicAdd(&deg[eidx[n_edges + e]], 1);
}

// ---------------- CSR build: exclusive scan (single block) ----------------
__global__ void k_scan(const int* __restrict__ deg, int* __restrict__ offs,
                       int* __restrict__ cursor, int n) {
    __shared__ int part[1024];
    int tid = threadIdx.x;
    int chunk = (n + 1023) / 1024;
    int base = tid * chunk;
    int hi = base + chunk < n ? base + chunk : n;
    int sum = 0;
    for (int i = base; i < hi; i++) sum += deg[i];
    part[tid] = sum;
    __syncthreads();
    for (int off = 1; off < 1024; off <<= 1) {
        int v = (tid >= off) ? part[tid - off] : 0;
        __syncthreads();
        part[tid] += v;
        __syncthreads();
    }
    int run = (tid == 0) ? 0 : part[tid - 1];  // exclusive prefix of this chunk
    for (int i = base; i < hi; i++) {
        offs[i] = run;
        cursor[i] = run;
        run += deg[i];
    }
    if (tid == 0) offs[n] = part[1023];
}

// ---------------- CSR build: scatter edge ids into slots ----------------
__global__ void k_scatter(const int* __restrict__ eidx, int* __restrict__ cursor,
                          int* __restrict__ eid, int n_edges) {
    int e = blockIdx.x * blockDim.x + threadIdx.x;
    if (e >= n_edges) return;
    int t = eidx[n_edges + e];
    int pos = atomicAdd(&cursor[t], 1);
    eid[pos] = e;
}

// ---------------- W prep: decompose Wl|Wr|Wv into bf16 hi/lo, fragment order --
// Fragment order: elem index = ((ks*NCT + ct)*64 + lane)*8 + i
//   k  = ks*32 + 8*(lane>>4) + i   (B operand: 8 contiguous k per lane)
//   gc = ct*16 + (lane&15)         (concat col: 0..127=Wl, 128..255=Wr, 256..383=Wv)
__global__ void k_wprep(const float* __restrict__ Wl, const float* __restrict__ Wr,
                        const float* __restrict__ Wv,
                        __bf16* __restrict__ Whi, __bf16* __restrict__ Wlo) {
    int tid = blockIdx.x * blockDim.x + threadIdx.x;
    if (tid >= KSTEPS * NCT * 64) return;
    int l = tid & 63;
    int ctks = tid >> 6;
    int ct = ctks % NCT;
    int ks = ctks / NCT;
    int gc = ct * 16 + (l & 15);
    int m = gc >> 7;
    int c = gc & 127;
    const float* W = (m == 0) ? Wl : (m == 1) ? Wr : Wv;
    bf16x8 h8, l8;
#pragma unroll
    for (int i = 0; i < 8; i++) {
        int k = ks * 32 + ((l >> 4) << 3) + i;
        float w = W[k * HD + c];
        __bf16 hi = (__bf16)w;
        __bf16 lo = (__bf16)(w - (float)hi);
        h8[i] = hi;
        l8[i] = lo;
    }
    *(bf16x8*)(Whi + (size_t)tid * 8) = h8;
    *(bf16x8*)(Wlo + (size_t)tid * 8) = l8;
}

// ---------------- K1: node projections via MFMA (split-precision bf16) -------
// Block = 4 waves; wave w owns rows [blockIdx*64 + w*16, +16), all 384 cols.
// C = A_hi@W_hi + A_lo@W_hi + A_hi@W_lo  (~fp32-accurate; lo*lo term ~2^-18)
__global__ __launch_bounds__(256, 2) void k_projm(
    const float* __restrict__ nf,
    const __bf16* __restrict__ Whi, const __bf16* __restrict__ Wlo,
    const float* __restrict__ bl, const float* __restrict__ br,
    const float* __restrict__ bv,
    __hip_bfloat16* __restrict__ left, __hip_bfloat16* __restrict__ right,
    __hip_bfloat16* __restrict__ val, int n_nodes) {
    int l = threadIdx.x & 63;
    int wave = threadIdx.x >> 6;
    int row0 = blockIdx.x * 64 + wave * 16;
    if (row0 >= n_nodes) return;  // n_nodes % 16 == 0, so wave-level guard suffices
    int lr = l & 15, lg = l >> 4;
    const float* arow = nf + (size_t)(row0 + lr) * IN_F + lg * 8;

    const f32x4 zero = {0.f, 0.f, 0.f, 0.f};
    f32x4 acc[NCT];
#pragma unroll
    for (int ct = 0; ct < NCT; ct++) acc[ct] = zero;

    for (int ks = 0; ks < KSTEPS; ks++) {
        // A fragment: row = lr, k = ks*32 + lg*8 + i  (8 contiguous floats)
        f32x4 a0 = *(const f32x4*)(arow + ks * 32);
        f32x4 a1 = *(const f32x4*)(arow + ks * 32 + 4);
        bf16x8 ah, al;
#pragma unroll
        for (int i = 0; i < 4; i++) {
            __bf16 h = (__bf16)a0[i];
            ah[i] = h;
            al[i] = (__bf16)(a0[i] - (float)h);
        }
#pragma unroll
        for (int i = 0; i < 4; i++) {
            __bf16 h = (__bf16)a1[i];
            ah[4 + i] = h;
            al[4 + i] = (__bf16)(a1[i] - (float)h);
        }
        const bf16x8* wh = (const bf16x8*)(Whi) + (size_t)ks * NCT * 64 + l;
        const bf16x8* wl = (const bf16x8*)(Wlo) + (size_t)ks * NCT * 64 + l;
#pragma unroll
        for (int ct = 0; ct < NCT; ct++) {
            bf16x8 bh = wh[ct * 64];
            bf16x8 blo = wl[ct * 64];
            acc[ct] = __builtin_amdgcn_mfma_f32_16x16x32_bf16(ah, bh, acc[ct], 0, 0, 0);
            acc[ct] = __builtin_amdgcn_mfma_f32_16x16x32_bf16(al, bh, acc[ct], 0, 0, 0);
            acc[ct] = __builtin_amdgcn_mfma_f32_16x16x32_bf16(ah, blo, acc[ct], 0, 0, 0);
        }
    }

    // Epilogue: D layout col = lr, row = lg*4 + r  (m89-verified)
#pragma unroll
    for (int ct = 0; ct < NCT; ct++) {
        const int m = ct >> 3;               // 0=left, 1=right, 2=val (compile-time)
        int c = ((ct & 7) << 4) + lr;
        float bias = (m == 0) ? bl[c] : (m == 1) ? br[c] : bv[c];
        __hip_bfloat16* dst = (m == 0) ? left : (m == 1) ? right : val;
#pragma unroll
        for (int r = 0; r < 4; r++) {
            int row = row0 + lg * 4 + r;
            dst[(size_t)row * HD + c] = f2b(acc[ct][r] + bias);
        }
    }
}

// ---------------- K2: edge scores, es = exp(score), no atomics ----------
__global__ void k_escore(const int* __restrict__ eidx, const float* __restrict__ ef,
                         const float* __restrict__ We, const float* __restrict__ be,
                         const float* __restrict__ av,
                         const __hip_bfloat16* __restrict__ left,
                         const __hip_bfloat16* __restrict__ right,
                         __hip_bfloat16* __restrict__ es, int n_edges) {
    int gid = blockIdx.x * blockDim.x + threadIdx.x;
    int e = gid >> 3;
    int h = gid & 7;
    if (e >= n_edges) return;
    int s = eidx[e];
    int t = eidx[n_edges + e];
    float sc = be[h];
    const float* efr = ef + (size_t)e * E_F;
#pragma unroll 8
    for (int k = 0; k < E_F; k++) sc += efr[k] * We[k * NUM_H + h];
    const __hip_bfloat16* L = left + (size_t)t * HD + h * DIM;
    const __hip_bfloat16* R = right + (size_t)s * HD + h * DIM;
#pragma unroll
    for (int d = 0; d < DIM; d++) {
        float x = b2f(L[d]) + b2f(R[d]);
        x = x > 0.0f ? x : NEG_SLOPE * x;
        sc += x * av[h * DIM + d];
    }
    es[(size_t)e * NUM_H + h] = f2b(expf(sc));
}

// ---------------- K3: gather-aggregate per node + normalize ----------------
__global__ void k_agg(const int* __restrict__ offs, const int* __restrict__ eid,
                      const int* __restrict__ eidx,
                      const __hip_bfloat16* __restrict__ es,
                      const __hip_bfloat16* __restrict__ val,
                      float* __restrict__ nagg, int n_nodes) {
    int t = blockIdx.x;
    if (t >= n_nodes) return;
    int j = threadIdx.x;  // 0..127
    int h = j >> 4;
    int beg = offs[t], end = offs[t + 1];
    float acc = 0.0f, wsum = 0.0f;
    for (int i = beg; i < end; i++) {
        int e = eid[i];
        int s = eidx[e];  // source of this edge
        float w = b2f(es[(size_t)e * NUM_H + h]);
        acc += w * b2f(val[(size_t)s * HD + j]);
        wsum += w;
    }
    nagg[(size_t)t * HD + j] = acc / (wsum + 1e-10f);
}

// ---------------- K4: output projection, NB nodes per block ----------------
__global__ void k_out(const float* __restrict__ nagg, const float* __restrict__ Wo,
                      const float* __restrict__ bo, float* __restrict__ out, int n_nodes) {
    __shared__ float srow[NB][HD];
    int node0 = blockIdx.x * NB;
    int j = threadIdx.x;  // 0..127
    for (int i = j; i < NB * HD; i += 128)
        srow[i / HD][i % HD] = nagg[(size_t)node0 * HD + i];
    __syncthreads();
    float a[NB];
    float b = bo[j];
#pragma unroll
    for (int n = 0; n < NB; n++) a[n] = b;
    for (int k = 0; k < HD; k++) {
        float w = Wo[k * HD + j];
#pragma unroll
        for (int n = 0; n < NB; n++) a[n] += srow[n][k] * w;
    }
#pragma unroll
    for (int n = 0; n < NB; n++) out[(size_t)(node0 + n) * HD + j] = a[n];
}

extern "C" void kernel_launch(void* const* d_in, const int* in_sizes, int n_in,
                              void* d_out, int out_size, void* d_ws, size_t ws_size,
                              hipStream_t stream) {
    const float* nf = (const float*)d_in[0];
    const int* eidx = (const int*)d_in[1];
    const float* ef = (const float*)d_in[2];
    const float* Wl = (const float*)d_in[3];
    const float* bl = (const float*)d_in[4];
    const float* Wr = (const float*)d_in[5];
    const float* br = (const float*)d_in[6];
    const float* We = (const float*)d_in[7];
    const float* be = (const float*)d_in[8];
    const float* av = (const float*)d_in[9];
    const float* Wv = (const float*)d_in[10];
    const float* bv = (const float*)d_in[11];
    const float* Wo = (const float*)d_in[12];
    const float* bo = (const float*)d_in[13];
    float* out = (float*)d_out;

    const int n_nodes = in_sizes[0] / IN_F;   // 50000
    const int n_edges = in_sizes[1] / 2;      // 800000
    const size_t NHD = (size_t)n_nodes * HD;  // 6.4M

    // workspace layout (~42.3 MB — IDENTICAL footprint to the verified baseline):
    //   [256B pad]
    //   left   bf16 [NHD]      12.8 MB   } nagg f32 [NHD] (25.6 MB) overlays
    //   right  bf16 [NHD]      12.8 MB   } left+right after escore is done
    //   es     bf16 [E*8]      12.8 MB   } Whi/Wlo bf16 (384 KB) overlay the
    //                                    } START of es: written by k_wprep,
    //                                    } read by k_projm, dead once k_escore
    //                                    } (stream-ordered after) rewrites es.
    //   deg    int  [N]        200 KB
    //   offs   int  [N+1]      200 KB
    //   cursor int  [N]        200 KB
    //   eid    int  [E]        3.2 MB
    // val bf16 [NHD] lives in d_out's first half; k_out rewrites d_out later.
    char* base = (char*)d_ws;
    __hip_bfloat16* left  = (__hip_bfloat16*)(base + 256);
    __hip_bfloat16* right = left + NHD;
    __hip_bfloat16* es    = right + NHD;
    int* deg    = (int*)(es + (size_t)n_edges * NUM_H);
    int* offs   = deg + n_nodes;
    int* cursor = offs + n_nodes + 1;
    int* eid    = cursor + n_nodes;
    __bf16* Whi = (__bf16*)es;          // overlay (es region is 12.8 MB; we use 384 KB)
    __bf16* Wlo = Whi + (size_t)WELEMS;
    float* nagg = (float*)left;
    __hip_bfloat16* val = (__hip_bfloat16*)d_out;

    int eb = (n_edges + 255) / 256;  // 3125

    // weight decomposition + pack (tiny; stays L2-resident for k_projm)
    k_wprep<<<(KSTEPS * NCT * 64 + 255) / 256, 256, 0, stream>>>(Wl, Wr, Wv, Whi, Wlo);

    // CSR build
    k_zero_int<<<64, 256, 0, stream>>>(deg, n_nodes);
    k_hist<<<eb, 256, 0, stream>>>(eidx, deg, n_edges);
    k_scan<<<1, 1024, 0, stream>>>(deg, offs, cursor, n_nodes);
    k_scatter<<<eb, 256, 0, stream>>>(eidx, cursor, eid, n_edges);

    // projections via MFMA (writes left/right in ws, val in d_out)
    k_projm<<<(n_nodes + 63) / 64, 256, 0, stream>>>(nf, Whi, Wlo, bl, br, bv,
                                                     left, right, val, n_nodes);

    // edge scores (also frees Whi/Wlo by overwriting es)
    k_escore<<<((size_t)n_edges * NUM_H + 255) / 256, 256, 0, stream>>>(
        eidx, ef, We, be, av, left, right, es, n_edges);

    // gather-aggregate + normalize (left/right dead -> nagg overlays them)
    k_agg<<<n_nodes, 128, 0, stream>>>(offs, eid, eidx, es, val, nagg, n_nodes);

    // output projection (fully rewrites d_out)
    k_out<<<n_nodes / NB, 128, 0, stream>>>(nagg, Wo, bo, out, n_nodes);
}

// Round 4
// 860.690 us; speedup vs baseline: 1.2229x; 1.0694x over previous
//
#include <hip/hip_runtime.h>
#include <hip/hip_bf16.h>
#include <stdint.h>

#define NUM_H 8
#define DIM 16
#define HD 128
#define IN_F 256
#define E_F 64
#define NEG_SLOPE 0.2f
#define NB 8  // nodes per block in k_out
#define EB 32 // edges per block in k_escore

#define NCT 24    // col-tiles: 3 matrices * 128 cols / 16
#define KSTEPS 8  // 256 / 32
#define WELEMS (KSTEPS * NCT * 64 * 8)  // 98304 bf16 elems per W plane (192 KB)

typedef __bf16 bf16x8 __attribute__((ext_vector_type(8)));
typedef float f32x4 __attribute__((ext_vector_type(4)));
typedef short short8 __attribute__((ext_vector_type(8)));

__device__ __forceinline__ float b2f(__hip_bfloat16 x) { return __bfloat162float(x); }
__device__ __forceinline__ __hip_bfloat16 f2b(float x) { return __float2bfloat16(x); }
__device__ __forceinline__ float bs2f(short s) {
    uint32_t u = ((uint32_t)(uint16_t)s) << 16;
    return __builtin_bit_cast(float, u);
}

// ---------------- zero int array (deg) ----------------
__global__ void k_zero_int(int* p, int n) {
    int i = blockIdx.x * blockDim.x + threadIdx.x;
    int stride = gridDim.x * blockDim.x;
    for (; i < n; i += stride) p[i] = 0;
}

// ---------------- CSR build: histogram of targets ----------------
__global__ void k_hist(const int* __restrict__ eidx, int* __restrict__ deg, int n_edges) {
    int e = blockIdx.x * blockDim.x + threadIdx.x;
    if (e < n_edges) atomicAdd(&deg[eidx[n_edges + e]], 1);
}

// ---------------- CSR build: exclusive scan (single block) ----------------
__global__ void k_scan(const int* __restrict__ deg, int* __restrict__ offs,
                       int* __restrict__ cursor, int n) {
    __shared__ int part[1024];
    int tid = threadIdx.x;
    int chunk = (n + 1023) / 1024;
    int base = tid * chunk;
    int hi = base + chunk < n ? base + chunk : n;
    int sum = 0;
    for (int i = base; i < hi; i++) sum += deg[i];
    part[tid] = sum;
    __syncthreads();
    for (int off = 1; off < 1024; off <<= 1) {
        int v = (tid >= off) ? part[tid - off] : 0;
        __syncthreads();
        part[tid] += v;
        __syncthreads();
    }
    int run = (tid == 0) ? 0 : part[tid - 1];  // exclusive prefix of this chunk
    for (int i = base; i < hi; i++) {
        offs[i] = run;
        cursor[i] = run;
        run += deg[i];
    }
    if (tid == 0) offs[n] = part[1023];
}

// ---------------- CSR build: scatter edge ids into slots ----------------
__global__ void k_scatter(const int* __restrict__ eidx, int* __restrict__ cursor,
                          int* __restrict__ eid, int n_edges) {
    int e = blockIdx.x * blockDim.x + threadIdx.x;
    if (e >= n_edges) return;
    int t = eidx[n_edges + e];
    int pos = atomicAdd(&cursor[t], 1);
    eid[pos] = e;
}

// ---------------- W prep: decompose Wl|Wr|Wv into bf16 hi/lo, fragment order --
// Fragment order: elem index = ((ks*NCT + ct)*64 + lane)*8 + i
//   k  = ks*32 + 8*(lane>>4) + i   (B operand: 8 contiguous k per lane)
//   gc = ct*16 + (lane&15)         (concat col: 0..127=Wl, 128..255=Wr, 256..383=Wv)
__global__ void k_wprep(const float* __restrict__ Wl, const float* __restrict__ Wr,
                        const float* __restrict__ Wv,
                        __bf16* __restrict__ Whi, __bf16* __restrict__ Wlo) {
    int tid = blockIdx.x * blockDim.x + threadIdx.x;
    if (tid >= KSTEPS * NCT * 64) return;
    int l = tid & 63;
    int ctks = tid >> 6;
    int ct = ctks % NCT;
    int ks = ctks / NCT;
    int gc = ct * 16 + (l & 15);
    int m = gc >> 7;
    int c = gc & 127;
    const float* W = (m == 0) ? Wl : (m == 1) ? Wr : Wv;
    bf16x8 h8, l8;
#pragma unroll
    for (int i = 0; i < 8; i++) {
        int k = ks * 32 + ((l >> 4) << 3) + i;
        float w = W[k * HD + c];
        __bf16 hi = (__bf16)w;
        __bf16 lo = (__bf16)(w - (float)hi);
        h8[i] = hi;
        l8[i] = lo;
    }
    *(bf16x8*)(Whi + (size_t)tid * 8) = h8;
    *(bf16x8*)(Wlo + (size_t)tid * 8) = l8;
}

// ---------------- K1: node projections via MFMA (split-precision bf16) -------
// Block = 4 waves; wave w owns rows [blockIdx*64 + w*16, +16), all 384 cols.
// C = A_hi@W_hi + A_lo@W_hi + A_hi@W_lo  (~fp32-accurate; lo*lo term ~2^-18)
__global__ __launch_bounds__(256, 2) void k_projm(
    const float* __restrict__ nf,
    const __bf16* __restrict__ Whi, const __bf16* __restrict__ Wlo,
    const float* __restrict__ bl, const float* __restrict__ br,
    const float* __restrict__ bv,
    __hip_bfloat16* __restrict__ left, __hip_bfloat16* __restrict__ right,
    __hip_bfloat16* __restrict__ val, int n_nodes) {
    int l = threadIdx.x & 63;
    int wave = threadIdx.x >> 6;
    int row0 = blockIdx.x * 64 + wave * 16;
    if (row0 >= n_nodes) return;  // n_nodes % 16 == 0, so wave-level guard suffices
    int lr = l & 15, lg = l >> 4;
    const float* arow = nf + (size_t)(row0 + lr) * IN_F + lg * 8;

    const f32x4 zero = {0.f, 0.f, 0.f, 0.f};
    f32x4 acc[NCT];
#pragma unroll
    for (int ct = 0; ct < NCT; ct++) acc[ct] = zero;

    for (int ks = 0; ks < KSTEPS; ks++) {
        // A fragment: row = lr, k = ks*32 + lg*8 + i  (8 contiguous floats)
        f32x4 a0 = *(const f32x4*)(arow + ks * 32);
        f32x4 a1 = *(const f32x4*)(arow + ks * 32 + 4);
        bf16x8 ah, al;
#pragma unroll
        for (int i = 0; i < 4; i++) {
            __bf16 h = (__bf16)a0[i];
            ah[i] = h;
            al[i] = (__bf16)(a0[i] - (float)h);
        }
#pragma unroll
        for (int i = 0; i < 4; i++) {
            __bf16 h = (__bf16)a1[i];
            ah[4 + i] = h;
            al[4 + i] = (__bf16)(a1[i] - (float)h);
        }
        const bf16x8* wh = (const bf16x8*)(Whi) + (size_t)ks * NCT * 64 + l;
        const bf16x8* wl = (const bf16x8*)(Wlo) + (size_t)ks * NCT * 64 + l;
#pragma unroll
        for (int ct = 0; ct < NCT; ct++) {
            bf16x8 bh = wh[ct * 64];
            bf16x8 blo = wl[ct * 64];
            acc[ct] = __builtin_amdgcn_mfma_f32_16x16x32_bf16(ah, bh, acc[ct], 0, 0, 0);
            acc[ct] = __builtin_amdgcn_mfma_f32_16x16x32_bf16(al, bh, acc[ct], 0, 0, 0);
            acc[ct] = __builtin_amdgcn_mfma_f32_16x16x32_bf16(ah, blo, acc[ct], 0, 0, 0);
        }
    }

    // Epilogue: D layout col = lr, row = lg*4 + r  (m89-verified)
#pragma unroll
    for (int ct = 0; ct < NCT; ct++) {
        const int m = ct >> 3;               // 0=left, 1=right, 2=val (compile-time)
        int c = ((ct & 7) << 4) + lr;
        float bias = (m == 0) ? bl[c] : (m == 1) ? br[c] : bv[c];
        __hip_bfloat16* dst = (m == 0) ? left : (m == 1) ? right : val;
#pragma unroll
        for (int r = 0; r < 4; r++) {
            int row = row0 + lg * 4 + r;
            dst[(size_t)row * HD + c] = f2b(acc[ct][r] + bias);
        }
    }
}

// ---------------- K2: edge scores, LDS-staged ef + vectorized gathers --------
// Block = 256 threads = 32 edges x 8 heads. ef rows staged via coalesced
// float4 into padded LDS [EB][68] (row-starts hit banks 4e mod 32 -> b128
// reads conflict-free; 8 head-lanes broadcast).
__global__ __launch_bounds__(256) void k_escore(
    const int* __restrict__ eidx, const float* __restrict__ ef,
    const float* __restrict__ We, const float* __restrict__ be,
    const float* __restrict__ av,
    const __hip_bfloat16* __restrict__ left,
    const __hip_bfloat16* __restrict__ right,
    __hip_bfloat16* __restrict__ es, int n_edges) {
    __shared__ float sef[EB][68];
    int tid = threadIdx.x;
    int e0 = blockIdx.x * EB;
    // stage ef[e0..e0+EB) -- fully contiguous float4 stream
    {
        const f32x4* src = (const f32x4*)(ef + (size_t)e0 * E_F);
        int lim = (n_edges - e0) * (E_F / 4);  // guard for ragged tail
        if (lim > EB * (E_F / 4)) lim = EB * (E_F / 4);
#pragma unroll 2
        for (int i = tid; i < lim; i += 256) {
            f32x4 v = src[i];
            int le = i >> 4;          // i*4/64
            int k = (i & 15) << 2;    // (i*4)%64
            *(f32x4*)&sef[le][k] = v;
        }
    }
    __syncthreads();
    int le = tid >> 3;
    int h = tid & 7;
    int e = e0 + le;
    if (e >= n_edges) return;
    int s = eidx[e];
    int t = eidx[n_edges + e];

    // ef @ We column h from LDS (16x ds_read_b128, conflict-free)
    float sc = be[h];
    const float* row = &sef[le][0];
#pragma unroll
    for (int k4 = 0; k4 < E_F / 4; k4++) {
        f32x4 v = *(const f32x4*)(row + k4 * 4);
        sc += v[0] * We[(k4 * 4 + 0) * NUM_H + h] + v[1] * We[(k4 * 4 + 1) * NUM_H + h] +
              v[2] * We[(k4 * 4 + 2) * NUM_H + h] + v[3] * We[(k4 * 4 + 3) * NUM_H + h];
    }

    // GATv2 score: vectorized 16B gathers of left[t], right[s] head-slices
    const short8* Lp = (const short8*)(left + (size_t)t * HD + h * DIM);
    const short8* Rp = (const short8*)(right + (size_t)s * HD + h * DIM);
    short8 l0 = Lp[0], l1 = Lp[1];
    short8 r0 = Rp[0], r1 = Rp[1];
    const float* avh = av + h * DIM;
#pragma unroll
    for (int d = 0; d < 8; d++) {
        float x = bs2f(l0[d]) + bs2f(r0[d]);
        x = x > 0.0f ? x : NEG_SLOPE * x;
        sc += x * avh[d];
    }
#pragma unroll
    for (int d = 0; d < 8; d++) {
        float x = bs2f(l1[d]) + bs2f(r1[d]);
        x = x > 0.0f ? x : NEG_SLOPE * x;
        sc += x * avh[8 + d];
    }
    es[(size_t)e * NUM_H + h] = f2b(expf(sc));
}

// ---------------- K3: gather-aggregate per node + normalize ----------------
__global__ void k_agg(const int* __restrict__ offs, const int* __restrict__ eid,
                      const int* __restrict__ eidx,
                      const __hip_bfloat16* __restrict__ es,
                      const __hip_bfloat16* __restrict__ val,
                      float* __restrict__ nagg, int n_nodes) {
    int t = blockIdx.x;
    if (t >= n_nodes) return;
    int j = threadIdx.x;  // 0..127
    int h = j >> 4;
    int beg = offs[t], end = offs[t + 1];
    float acc = 0.0f, wsum = 0.0f;
    for (int i = beg; i < end; i++) {
        int e = eid[i];
        int s = eidx[e];  // source of this edge
        float w = b2f(es[(size_t)e * NUM_H + h]);
        acc += w * b2f(val[(size_t)s * HD + j]);
        wsum += w;
    }
    nagg[(size_t)t * HD + j] = acc / (wsum + 1e-10f);
}

// ---------------- K4: output projection, NB nodes per block ----------------
__global__ void k_out(const float* __restrict__ nagg, const float* __restrict__ Wo,
                      const float* __restrict__ bo, float* __restrict__ out, int n_nodes) {
    __shared__ float srow[NB][HD];
    int node0 = blockIdx.x * NB;
    int j = threadIdx.x;  // 0..127
    for (int i = j; i < NB * HD; i += 128)
        srow[i / HD][i % HD] = nagg[(size_t)node0 * HD + i];
    __syncthreads();
    float a[NB];
    float b = bo[j];
#pragma unroll
    for (int n = 0; n < NB; n++) a[n] = b;
    for (int k = 0; k < HD; k++) {
        float w = Wo[k * HD + j];
#pragma unroll
        for (int n = 0; n < NB; n++) a[n] += srow[n][k] * w;
    }
#pragma unroll
    for (int n = 0; n < NB; n++) out[(size_t)(node0 + n) * HD + j] = a[n];
}

extern "C" void kernel_launch(void* const* d_in, const int* in_sizes, int n_in,
                              void* d_out, int out_size, void* d_ws, size_t ws_size,
                              hipStream_t stream) {
    const float* nf = (const float*)d_in[0];
    const int* eidx = (const int*)d_in[1];
    const float* ef = (const float*)d_in[2];
    const float* Wl = (const float*)d_in[3];
    const float* bl = (const float*)d_in[4];
    const float* Wr = (const float*)d_in[5];
    const float* br = (const float*)d_in[6];
    const float* We = (const float*)d_in[7];
    const float* be = (const float*)d_in[8];
    const float* av = (const float*)d_in[9];
    const float* Wv = (const float*)d_in[10];
    const float* bv = (const float*)d_in[11];
    const float* Wo = (const float*)d_in[12];
    const float* bo = (const float*)d_in[13];
    float* out = (float*)d_out;

    const int n_nodes = in_sizes[0] / IN_F;   // 50000
    const int n_edges = in_sizes[1] / 2;      // 800000
    const size_t NHD = (size_t)n_nodes * HD;  // 6.4M

    // workspace layout (~42.3 MB — identical footprint to verified baseline):
    //   [256B pad]
    //   left   bf16 [NHD]      12.8 MB   } nagg f32 [NHD] (25.6 MB) overlays
    //   right  bf16 [NHD]      12.8 MB   } left+right after escore is done
    //   es     bf16 [E*8]      12.8 MB   } Whi/Wlo bf16 (384 KB) overlay the
    //                                    } start of es (dead once k_escore runs)
    //   deg    int  [N]        200 KB
    //   offs   int  [N+1]      200 KB
    //   cursor int  [N]        200 KB
    //   eid    int  [E]        3.2 MB
    // val bf16 [NHD] lives in d_out's first half; k_out rewrites d_out later.
    char* base = (char*)d_ws;
    __hip_bfloat16* left  = (__hip_bfloat16*)(base + 256);
    __hip_bfloat16* right = left + NHD;
    __hip_bfloat16* es    = right + NHD;
    int* deg    = (int*)(es + (size_t)n_edges * NUM_H);
    int* offs   = deg + n_nodes;
    int* cursor = offs + n_nodes + 1;
    int* eid    = cursor + n_nodes;
    __bf16* Whi = (__bf16*)es;          // overlay (es region is 12.8 MB; we use 384 KB)
    __bf16* Wlo = Whi + (size_t)WELEMS;
    float* nagg = (float*)left;
    __hip_bfloat16* val = (__hip_bfloat16*)d_out;

    int eb = (n_edges + 255) / 256;  // 3125

    // weight decomposition + pack (tiny; stays L2-resident for k_projm)
    k_wprep<<<(KSTEPS * NCT * 64 + 255) / 256, 256, 0, stream>>>(Wl, Wr, Wv, Whi, Wlo);

    // CSR build
    k_zero_int<<<64, 256, 0, stream>>>(deg, n_nodes);
    k_hist<<<eb, 256, 0, stream>>>(eidx, deg, n_edges);
    k_scan<<<1, 1024, 0, stream>>>(deg, offs, cursor, n_nodes);
    k_scatter<<<eb, 256, 0, stream>>>(eidx, cursor, eid, n_edges);

    // projections via MFMA (writes left/right in ws, val in d_out)
    k_projm<<<(n_nodes + 63) / 64, 256, 0, stream>>>(nf, Whi, Wlo, bl, br, bv,
                                                     left, right, val, n_nodes);

    // edge scores (also frees Whi/Wlo by overwriting es)
    k_escore<<<(n_edges + EB - 1) / EB, 256, 0, stream>>>(
        eidx, ef, We, be, av, left, right, es, n_edges);

    // gather-aggregate + normalize (left/right dead -> nagg overlays them)
    k_agg<<<n_nodes, 128, 0, stream>>>(offs, eid, eidx, es, val, nagg, n_nodes);

    // output projection (fully rewrites d_out)
    k_out<<<n_nodes / NB, 128, 0, stream>>>(nagg, Wo, bo, out, n_nodes);
}

// Round 5
// 779.932 us; speedup vs baseline: 1.3495x; 1.1035x over previous
//
#include <hip/hip_runtime.h>
#include <hip/hip_bf16.h>
#include <stdint.h>

#define NUM_H 8
#define DIM 16
#define HD 128
#define IN_F 256
#define E_F 64
#define NEG_SLOPE 0.2f
#define NB 8  // nodes per block in k_out
#define EB 32 // edges per block in k_escore

#define NCT 24    // col-tiles: 3 matrices * 128 cols / 16
#define KSTEPS 8  // 256 / 32
#define WELEMS (KSTEPS * NCT * 64 * 8)  // 98304 bf16 elems per W plane (192 KB)

typedef __bf16 bf16x8 __attribute__((ext_vector_type(8)));
typedef float f32x4 __attribute__((ext_vector_type(4)));
typedef short short8 __attribute__((ext_vector_type(8)));

__device__ __forceinline__ float b2f(__hip_bfloat16 x) { return __bfloat162float(x); }
__device__ __forceinline__ __hip_bfloat16 f2b(float x) { return __float2bfloat16(x); }
__device__ __forceinline__ float bs2f(short s) {
    uint32_t u = ((uint32_t)(uint16_t)s) << 16;
    return __builtin_bit_cast(float, u);
}

// ---------------- zero int array (deg) ----------------
__global__ void k_zero_int(int* p, int n) {
    int i = blockIdx.x * blockDim.x + threadIdx.x;
    int stride = gridDim.x * blockDim.x;
    for (; i < n; i += stride) p[i] = 0;
}

// ---------------- CSR build: histogram of targets ----------------
__global__ void k_hist(const int* __restrict__ eidx, int* __restrict__ deg, int n_edges) {
    int e = blockIdx.x * blockDim.x + threadIdx.x;
    if (e < n_edges) atomicAdd(&deg[eidx[n_edges + e]], 1);
}

// ---------------- CSR build: exclusive scan (single block) ----------------
__global__ void k_scan(const int* __restrict__ deg, int* __restrict__ offs,
                       int* __restrict__ cursor, int n) {
    __shared__ int part[1024];
    int tid = threadIdx.x;
    int chunk = (n + 1023) / 1024;
    int base = tid * chunk;
    int hi = base + chunk < n ? base + chunk : n;
    int sum = 0;
    for (int i = base; i < hi; i++) sum += deg[i];
    part[tid] = sum;
    __syncthreads();
    for (int off = 1; off < 1024; off <<= 1) {
        int v = (tid >= off) ? part[tid - off] : 0;
        __syncthreads();
        part[tid] += v;
        __syncthreads();
    }
    int run = (tid == 0) ? 0 : part[tid - 1];  // exclusive prefix of this chunk
    for (int i = base; i < hi; i++) {
        offs[i] = run;
        cursor[i] = run;
        run += deg[i];
    }
    if (tid == 0) offs[n] = part[1023];
}

// ---------------- W prep: decompose Wl|Wr|Wv into bf16 hi/lo, fragment order --
// Fragment order: elem index = ((ks*NCT + ct)*64 + lane)*8 + i
//   k  = ks*32 + 8*(lane>>4) + i   (B operand: 8 contiguous k per lane)
//   gc = ct*16 + (lane&15)         (concat col: 0..127=Wl, 128..255=Wr, 256..383=Wv)
__global__ void k_wprep(const float* __restrict__ Wl, const float* __restrict__ Wr,
                        const float* __restrict__ Wv,
                        __bf16* __restrict__ Whi, __bf16* __restrict__ Wlo) {
    int tid = blockIdx.x * blockDim.x + threadIdx.x;
    if (tid >= KSTEPS * NCT * 64) return;
    int l = tid & 63;
    int ctks = tid >> 6;
    int ct = ctks % NCT;
    int ks = ctks / NCT;
    int gc = ct * 16 + (l & 15);
    int m = gc >> 7;
    int c = gc & 127;
    const float* W = (m == 0) ? Wl : (m == 1) ? Wr : Wv;
    bf16x8 h8, l8;
#pragma unroll
    for (int i = 0; i < 8; i++) {
        int k = ks * 32 + ((l >> 4) << 3) + i;
        float w = W[k * HD + c];
        __bf16 hi = (__bf16)w;
        __bf16 lo = (__bf16)(w - (float)hi);
        h8[i] = hi;
        l8[i] = lo;
    }
    *(bf16x8*)(Whi + (size_t)tid * 8) = h8;
    *(bf16x8*)(Wlo + (size_t)tid * 8) = l8;
}

// ---------------- K1: node projections via MFMA (split-precision bf16) -------
// Block = 4 waves; wave w owns rows [blockIdx*64 + w*16, +16), all 384 cols.
// C = A_hi@W_hi + A_lo@W_hi + A_hi@W_lo  (~fp32-accurate; lo*lo term ~2^-18)
__global__ __launch_bounds__(256, 2) void k_projm(
    const float* __restrict__ nf,
    const __bf16* __restrict__ Whi, const __bf16* __restrict__ Wlo,
    const float* __restrict__ bl, const float* __restrict__ br,
    const float* __restrict__ bv,
    __hip_bfloat16* __restrict__ left, __hip_bfloat16* __restrict__ right,
    __hip_bfloat16* __restrict__ val, int n_nodes) {
    int l = threadIdx.x & 63;
    int wave = threadIdx.x >> 6;
    int row0 = blockIdx.x * 64 + wave * 16;
    if (row0 >= n_nodes) return;  // n_nodes % 16 == 0, so wave-level guard suffices
    int lr = l & 15, lg = l >> 4;
    const float* arow = nf + (size_t)(row0 + lr) * IN_F + lg * 8;

    const f32x4 zero = {0.f, 0.f, 0.f, 0.f};
    f32x4 acc[NCT];
#pragma unroll
    for (int ct = 0; ct < NCT; ct++) acc[ct] = zero;

    for (int ks = 0; ks < KSTEPS; ks++) {
        // A fragment: row = lr, k = ks*32 + lg*8 + i  (8 contiguous floats)
        f32x4 a0 = *(const f32x4*)(arow + ks * 32);
        f32x4 a1 = *(const f32x4*)(arow + ks * 32 + 4);
        bf16x8 ah, al;
#pragma unroll
        for (int i = 0; i < 4; i++) {
            __bf16 h = (__bf16)a0[i];
            ah[i] = h;
            al[i] = (__bf16)(a0[i] - (float)h);
        }
#pragma unroll
        for (int i = 0; i < 4; i++) {
            __bf16 h = (__bf16)a1[i];
            ah[4 + i] = h;
            al[4 + i] = (__bf16)(a1[i] - (float)h);
        }
        const bf16x8* wh = (const bf16x8*)(Whi) + (size_t)ks * NCT * 64 + l;
        const bf16x8* wl = (const bf16x8*)(Wlo) + (size_t)ks * NCT * 64 + l;
#pragma unroll
        for (int ct = 0; ct < NCT; ct++) {
            bf16x8 bh = wh[ct * 64];
            bf16x8 blo = wl[ct * 64];
            acc[ct] = __builtin_amdgcn_mfma_f32_16x16x32_bf16(ah, bh, acc[ct], 0, 0, 0);
            acc[ct] = __builtin_amdgcn_mfma_f32_16x16x32_bf16(al, bh, acc[ct], 0, 0, 0);
            acc[ct] = __builtin_amdgcn_mfma_f32_16x16x32_bf16(ah, blo, acc[ct], 0, 0, 0);
        }
    }

    // Epilogue: D layout col = lr, row = lg*4 + r  (m89-verified)
#pragma unroll
    for (int ct = 0; ct < NCT; ct++) {
        const int m = ct >> 3;               // 0=left, 1=right, 2=val (compile-time)
        int c = ((ct & 7) << 4) + lr;
        float bias = (m == 0) ? bl[c] : (m == 1) ? br[c] : bv[c];
        __hip_bfloat16* dst = (m == 0) ? left : (m == 1) ? right : val;
#pragma unroll
        for (int r = 0; r < 4; r++) {
            int row = row0 + lg * 4 + r;
            dst[(size_t)row * HD + c] = f2b(acc[ct][r] + bias);
        }
    }
}

// ---------------- K2: edge scores + CSR scatter (fused) ---------------------
// Block = 256 threads = 32 edges x 8 heads. ef staged via coalesced float4
// into padded LDS [EB][68]. Each edge claims its CSR slot (atomicAdd on
// cursor, lane h==0, shfl-broadcast) and writes srcs[pos] + es_csr[pos*8+h]
// in CSR order so k_agg's reads are fully sequential.
__global__ __launch_bounds__(256) void k_escore(
    const int* __restrict__ eidx, const float* __restrict__ ef,
    const float* __restrict__ We, const float* __restrict__ be,
    const float* __restrict__ av,
    const __hip_bfloat16* __restrict__ left,
    const __hip_bfloat16* __restrict__ right,
    int* __restrict__ cursor, int* __restrict__ srcs,
    __hip_bfloat16* __restrict__ es_csr, int n_edges) {
    __shared__ float sef[EB][68];
    int tid = threadIdx.x;
    int e0 = blockIdx.x * EB;
    // stage ef[e0..e0+EB) -- fully contiguous float4 stream
    {
        const f32x4* src = (const f32x4*)(ef + (size_t)e0 * E_F);
        int lim = (n_edges - e0) * (E_F / 4);  // guard for ragged tail
        if (lim > EB * (E_F / 4)) lim = EB * (E_F / 4);
#pragma unroll 2
        for (int i = tid; i < lim; i += 256) {
            f32x4 v = src[i];
            int le = i >> 4;          // i*4/64
            int k = (i & 15) << 2;    // (i*4)%64
            *(f32x4*)&sef[le][k] = v;
        }
    }
    __syncthreads();
    int le = tid >> 3;
    int h = tid & 7;
    int e = e0 + le;
    if (e >= n_edges) return;
    int s = eidx[e];
    int t = eidx[n_edges + e];

    // claim CSR slot (one lane per edge), broadcast within the 8-lane group
    int lane = tid & 63;
    int pos = 0;
    if (h == 0) pos = atomicAdd(&cursor[t], 1);
    pos = __shfl(pos, lane & ~7);

    // ef @ We column h from LDS (16x ds_read_b128, conflict-free)
    float sc = be[h];
    const float* row = &sef[le][0];
#pragma unroll
    for (int k4 = 0; k4 < E_F / 4; k4++) {
        f32x4 v = *(const f32x4*)(row + k4 * 4);
        sc += v[0] * We[(k4 * 4 + 0) * NUM_H + h] + v[1] * We[(k4 * 4 + 1) * NUM_H + h] +
              v[2] * We[(k4 * 4 + 2) * NUM_H + h] + v[3] * We[(k4 * 4 + 3) * NUM_H + h];
    }

    // GATv2 score: vectorized 16B gathers of left[t], right[s] head-slices
    const short8* Lp = (const short8*)(left + (size_t)t * HD + h * DIM);
    const short8* Rp = (const short8*)(right + (size_t)s * HD + h * DIM);
    short8 l0 = Lp[0], l1 = Lp[1];
    short8 r0 = Rp[0], r1 = Rp[1];
    const float* avh = av + h * DIM;
#pragma unroll
    for (int d = 0; d < 8; d++) {
        float x = bs2f(l0[d]) + bs2f(r0[d]);
        x = x > 0.0f ? x : NEG_SLOPE * x;
        sc += x * avh[d];
    }
#pragma unroll
    for (int d = 0; d < 8; d++) {
        float x = bs2f(l1[d]) + bs2f(r1[d]);
        x = x > 0.0f ? x : NEG_SLOPE * x;
        sc += x * avh[8 + d];
    }
    if (h == 0) srcs[pos] = s;
    es_csr[(size_t)pos * NUM_H + h] = f2b(expf(sc));
}

// ---------------- K3: gather-aggregate, 1 wave/node, 4 edges in flight ------
// lane = sub*16 + c16: sub = edge-subgroup (0..3), c16 = 16B chunk of the
// 256B val row (head h = c16>>1). Each lane: short8 (16B) load -> 1KB/instr
// coalescing, 4 independent row-gathers per iteration. Butterfly over
// sub (xor 16,32) folds partial sums; lanes sub==0 write the row.
__global__ __launch_bounds__(64) void k_agg(
    const int* __restrict__ offs, const int* __restrict__ srcs,
    const __hip_bfloat16* __restrict__ es_csr,
    const __hip_bfloat16* __restrict__ val,
    float* __restrict__ nagg, int n_nodes) {
    int t = blockIdx.x;
    if (t >= n_nodes) return;
    int lane = threadIdx.x;
    int sub = lane >> 4;
    int c16 = lane & 15;
    int h = c16 >> 1;
    int beg = offs[t], end = offs[t + 1];

    float acc[8] = {0.f, 0.f, 0.f, 0.f, 0.f, 0.f, 0.f, 0.f};
    float wsum = 0.0f;
#pragma unroll 2
    for (int i0 = beg; i0 < end; i0 += 4) {
        int i = i0 + sub;
        bool act = i < end;
        int ii = act ? i : beg;                       // safe address for inactive lanes
        int s = srcs[ii];                             // sequential (broadcast x16)
        float w = b2f(es_csr[(size_t)ii * NUM_H + h]);  // sequential stream
        if (!act) w = 0.0f;
        short8 v = *(const short8*)(val + (size_t)s * HD + c16 * 8);  // 16B gather
        wsum += w;
#pragma unroll
        for (int d = 0; d < 8; d++) acc[d] += w * bs2f(v[d]);
    }
    // fold the 4 edge-subgroups (lanes differing only in sub)
#pragma unroll
    for (int m = 16; m <= 32; m <<= 1) {
        wsum += __shfl_xor(wsum, m);
#pragma unroll
        for (int d = 0; d < 8; d++) acc[d] += __shfl_xor(acc[d], m);
    }
    if (sub == 0) {
        float inv = 1.0f / (wsum + 1e-10f);
        f32x4 o0, o1;
#pragma unroll
        for (int d = 0; d < 4; d++) { o0[d] = acc[d] * inv; o1[d] = acc[4 + d] * inv; }
        float* dst = nagg + (size_t)t * HD + c16 * 8;
        *(f32x4*)dst = o0;
        *(f32x4*)(dst + 4) = o1;
    }
}

// ---------------- K4: output projection, NB nodes per block ----------------
__global__ void k_out(const float* __restrict__ nagg, const float* __restrict__ Wo,
                      const float* __restrict__ bo, float* __restrict__ out, int n_nodes) {
    __shared__ float srow[NB][HD];
    int node0 = blockIdx.x * NB;
    int j = threadIdx.x;  // 0..127
    for (int i = j; i < NB * HD; i += 128)
        srow[i / HD][i % HD] = nagg[(size_t)node0 * HD + i];
    __syncthreads();
    float a[NB];
    float b = bo[j];
#pragma unroll
    for (int n = 0; n < NB; n++) a[n] = b;
    for (int k = 0; k < HD; k++) {
        float w = Wo[k * HD + j];
#pragma unroll
        for (int n = 0; n < NB; n++) a[n] += srow[n][k] * w;
    }
#pragma unroll
    for (int n = 0; n < NB; n++) out[(size_t)(node0 + n) * HD + j] = a[n];
}

extern "C" void kernel_launch(void* const* d_in, const int* in_sizes, int n_in,
                              void* d_out, int out_size, void* d_ws, size_t ws_size,
                              hipStream_t stream) {
    const float* nf = (const float*)d_in[0];
    const int* eidx = (const int*)d_in[1];
    const float* ef = (const float*)d_in[2];
    const float* Wl = (const float*)d_in[3];
    const float* bl = (const float*)d_in[4];
    const float* Wr = (const float*)d_in[5];
    const float* br = (const float*)d_in[6];
    const float* We = (const float*)d_in[7];
    const float* be = (const float*)d_in[8];
    const float* av = (const float*)d_in[9];
    const float* Wv = (const float*)d_in[10];
    const float* bv = (const float*)d_in[11];
    const float* Wo = (const float*)d_in[12];
    const float* bo = (const float*)d_in[13];
    float* out = (float*)d_out;

    const int n_nodes = in_sizes[0] / IN_F;   // 50000
    const int n_edges = in_sizes[1] / 2;      // 800000
    const size_t NHD = (size_t)n_nodes * HD;  // 6.4M

    // workspace layout (~42.3 MB — identical footprint to verified baseline):
    //   [256B pad]
    //   left   bf16 [NHD]      12.8 MB   } nagg f32 [NHD] (25.6 MB) overlays
    //   right  bf16 [NHD]      12.8 MB   } left+right after escore is done
    //   es_csr bf16 [E*8]      12.8 MB   } Whi/Wlo bf16 (384 KB) overlay the
    //                                    } start (dead once k_escore runs)
    //   deg    int  [N]        200 KB
    //   offs   int  [N+1]      200 KB
    //   cursor int  [N]        200 KB
    //   srcs   int  [E]        3.2 MB  (CSR-ordered source node per slot)
    // val bf16 [NHD] lives in d_out's first half; k_out rewrites d_out later.
    char* base = (char*)d_ws;
    __hip_bfloat16* left  = (__hip_bfloat16*)(base + 256);
    __hip_bfloat16* right = left + NHD;
    __hip_bfloat16* es_csr = right + NHD;
    int* deg    = (int*)(es_csr + (size_t)n_edges * NUM_H);
    int* offs   = deg + n_nodes;
    int* cursor = offs + n_nodes + 1;
    int* srcs   = cursor + n_nodes;
    __bf16* Whi = (__bf16*)es_csr;      // overlay (region is 12.8 MB; we use 384 KB)
    __bf16* Wlo = Whi + (size_t)WELEMS;
    float* nagg = (float*)left;
    __hip_bfloat16* val = (__hip_bfloat16*)d_out;

    int eb = (n_edges + 255) / 256;  // 3125

    // weight decomposition + pack (tiny; stays L2-resident for k_projm)
    k_wprep<<<(KSTEPS * NCT * 64 + 255) / 256, 256, 0, stream>>>(Wl, Wr, Wv, Whi, Wlo);

    // CSR build (histogram + scan only; scatter is fused into k_escore)
    k_zero_int<<<64, 256, 0, stream>>>(deg, n_nodes);
    k_hist<<<eb, 256, 0, stream>>>(eidx, deg, n_edges);
    k_scan<<<1, 1024, 0, stream>>>(deg, offs, cursor, n_nodes);

    // projections via MFMA (writes left/right in ws, val in d_out)
    k_projm<<<(n_nodes + 63) / 64, 256, 0, stream>>>(nf, Whi, Wlo, bl, br, bv,
                                                     left, right, val, n_nodes);

    // edge scores + CSR scatter (overwrites Whi/Wlo region with es_csr)
    k_escore<<<(n_edges + EB - 1) / EB, 256, 0, stream>>>(
        eidx, ef, We, be, av, left, right, cursor, srcs, es_csr, n_edges);

    // gather-aggregate + normalize (left/right dead -> nagg overlays them)
    k_agg<<<n_nodes, 64, 0, stream>>>(offs, srcs, es_csr, val, nagg, n_nodes);

    // output projection (fully rewrites d_out)
    k_out<<<n_nodes / NB, 128, 0, stream>>>(nagg, Wo, bo, out, n_nodes);
}

// Round 6
// 758.887 us; speedup vs baseline: 1.3870x; 1.0277x over previous
//
#include <hip/hip_runtime.h>
#include <hip/hip_bf16.h>
#include <stdint.h>

#define NUM_H 8
#define DIM 16
#define HD 128
#define IN_F 256
#define E_F 64
#define NEG_SLOPE 0.2f
#define NB 8  // nodes per block in k_out
#define EB 32 // edges per block in k_escore

#define NCT 24    // col-tiles: 3 matrices * 128 cols / 16
#define KSTEPS 8  // 256 / 32
#define WELEMS (KSTEPS * NCT * 64 * 8)  // 98304 bf16 elems per W plane (192 KB)

typedef __bf16 bf16x8 __attribute__((ext_vector_type(8)));
typedef float f32x4 __attribute__((ext_vector_type(4)));
typedef short short8 __attribute__((ext_vector_type(8)));

__device__ __forceinline__ float b2f(__hip_bfloat16 x) { return __bfloat162float(x); }
__device__ __forceinline__ __hip_bfloat16 f2b(float x) { return __float2bfloat16(x); }
__device__ __forceinline__ float bs2f(short s) {
    uint32_t u = ((uint32_t)(uint16_t)s) << 16;
    return __builtin_bit_cast(float, u);
}

// ---------------- zero int array (deg) ----------------
__global__ void k_zero_int(int* p, int n) {
    int i = blockIdx.x * blockDim.x + threadIdx.x;
    int stride = gridDim.x * blockDim.x;
    for (; i < n; i += stride) p[i] = 0;
}

// ---------------- CSR build: histogram of targets ----------------
__global__ void k_hist(const int* __restrict__ eidx, int* __restrict__ deg, int n_edges) {
    int e = blockIdx.x * blockDim.x + threadIdx.x;
    if (e < n_edges) atomicAdd(&deg[eidx[n_edges + e]], 1);
}

// ---------------- CSR build: exclusive scan (single block) ----------------
__global__ void k_scan(const int* __restrict__ deg, int* __restrict__ offs,
                       int* __restrict__ cursor, int n) {
    __shared__ int part[1024];
    int tid = threadIdx.x;
    int chunk = (n + 1023) / 1024;
    int base = tid * chunk;
    int hi = base + chunk < n ? base + chunk : n;
    int sum = 0;
    for (int i = base; i < hi; i++) sum += deg[i];
    part[tid] = sum;
    __syncthreads();
    for (int off = 1; off < 1024; off <<= 1) {
        int v = (tid >= off) ? part[tid - off] : 0;
        __syncthreads();
        part[tid] += v;
        __syncthreads();
    }
    int run = (tid == 0) ? 0 : part[tid - 1];  // exclusive prefix of this chunk
    for (int i = base; i < hi; i++) {
        offs[i] = run;
        cursor[i] = run;
        run += deg[i];
    }
    if (tid == 0) offs[n] = part[1023];
}

// ---------------- W prep: decompose Wl|Wr|Wv into bf16 hi/lo, fragment order --
// Fragment order: elem index = ((ks*NCT + ct)*64 + lane)*8 + i
//   k  = ks*32 + 8*(lane>>4) + i   (B operand: 8 contiguous k per lane)
//   gc = ct*16 + (lane&15)         (concat col: 0..127=Wl, 128..255=Wr, 256..383=Wv)
__global__ void k_wprep(const float* __restrict__ Wl, const float* __restrict__ Wr,
                        const float* __restrict__ Wv,
                        __bf16* __restrict__ Whi, __bf16* __restrict__ Wlo) {
    int tid = blockIdx.x * blockDim.x + threadIdx.x;
    if (tid >= KSTEPS * NCT * 64) return;
    int l = tid & 63;
    int ctks = tid >> 6;
    int ct = ctks % NCT;
    int ks = ctks / NCT;
    int gc = ct * 16 + (l & 15);
    int m = gc >> 7;
    int c = gc & 127;
    const float* W = (m == 0) ? Wl : (m == 1) ? Wr : Wv;
    bf16x8 h8, l8;
#pragma unroll
    for (int i = 0; i < 8; i++) {
        int k = ks * 32 + ((l >> 4) << 3) + i;
        float w = W[k * HD + c];
        __bf16 hi = (__bf16)w;
        __bf16 lo = (__bf16)(w - (float)hi);
        h8[i] = hi;
        l8[i] = lo;
    }
    *(bf16x8*)(Whi + (size_t)tid * 8) = h8;
    *(bf16x8*)(Wlo + (size_t)tid * 8) = l8;
}

// ---------------- K1: node projections via MFMA (split-precision bf16) -------
// Block = 4 waves; wave w owns rows [blockIdx*64 + w*16, +16), all 384 cols.
// C = A_hi@W_hi + A_lo@W_hi + A_hi@W_lo  (~fp32-accurate; lo*lo term ~2^-18)
__global__ __launch_bounds__(256, 2) void k_projm(
    const float* __restrict__ nf,
    const __bf16* __restrict__ Whi, const __bf16* __restrict__ Wlo,
    const float* __restrict__ bl, const float* __restrict__ br,
    const float* __restrict__ bv,
    __hip_bfloat16* __restrict__ left, __hip_bfloat16* __restrict__ right,
    __hip_bfloat16* __restrict__ val, int n_nodes) {
    int l = threadIdx.x & 63;
    int wave = threadIdx.x >> 6;
    int row0 = blockIdx.x * 64 + wave * 16;
    if (row0 >= n_nodes) return;  // n_nodes % 16 == 0, so wave-level guard suffices
    int lr = l & 15, lg = l >> 4;
    const float* arow = nf + (size_t)(row0 + lr) * IN_F + lg * 8;

    const f32x4 zero = {0.f, 0.f, 0.f, 0.f};
    f32x4 acc[NCT];
#pragma unroll
    for (int ct = 0; ct < NCT; ct++) acc[ct] = zero;

    for (int ks = 0; ks < KSTEPS; ks++) {
        // A fragment: row = lr, k = ks*32 + lg*8 + i  (8 contiguous floats)
        f32x4 a0 = *(const f32x4*)(arow + ks * 32);
        f32x4 a1 = *(const f32x4*)(arow + ks * 32 + 4);
        bf16x8 ah, al;
#pragma unroll
        for (int i = 0; i < 4; i++) {
            __bf16 h = (__bf16)a0[i];
            ah[i] = h;
            al[i] = (__bf16)(a0[i] - (float)h);
        }
#pragma unroll
        for (int i = 0; i < 4; i++) {
            __bf16 h = (__bf16)a1[i];
            ah[4 + i] = h;
            al[4 + i] = (__bf16)(a1[i] - (float)h);
        }
        const bf16x8* wh = (const bf16x8*)(Whi) + (size_t)ks * NCT * 64 + l;
        const bf16x8* wl = (const bf16x8*)(Wlo) + (size_t)ks * NCT * 64 + l;
#pragma unroll
        for (int ct = 0; ct < NCT; ct++) {
            bf16x8 bh = wh[ct * 64];
            bf16x8 blo = wl[ct * 64];
            acc[ct] = __builtin_amdgcn_mfma_f32_16x16x32_bf16(ah, bh, acc[ct], 0, 0, 0);
            acc[ct] = __builtin_amdgcn_mfma_f32_16x16x32_bf16(al, bh, acc[ct], 0, 0, 0);
            acc[ct] = __builtin_amdgcn_mfma_f32_16x16x32_bf16(ah, blo, acc[ct], 0, 0, 0);
        }
    }

    // Epilogue: D layout col = lr, row = lg*4 + r  (m89-verified)
#pragma unroll
    for (int ct = 0; ct < NCT; ct++) {
        const int m = ct >> 3;               // 0=left, 1=right, 2=val (compile-time)
        int c = ((ct & 7) << 4) + lr;
        float bias = (m == 0) ? bl[c] : (m == 1) ? br[c] : bv[c];
        __hip_bfloat16* dst = (m == 0) ? left : (m == 1) ? right : val;
#pragma unroll
        for (int r = 0; r < 4; r++) {
            int row = row0 + lg * 4 + r;
            dst[(size_t)row * HD + c] = f2b(acc[ct][r] + bias);
        }
    }
}

// ---------------- K2: edge scores, LDS-staged ef + vectorized gathers --------
// Round-4 form: sequential es write (edge order), no atomics -> low VGPR,
// high occupancy. CSR reordering happens in k_perm.
__global__ __launch_bounds__(256) void k_escore(
    const int* __restrict__ eidx, const float* __restrict__ ef,
    const float* __restrict__ We, const float* __restrict__ be,
    const float* __restrict__ av,
    const __hip_bfloat16* __restrict__ left,
    const __hip_bfloat16* __restrict__ right,
    __hip_bfloat16* __restrict__ es, int n_edges) {
    __shared__ float sef[EB][68];
    int tid = threadIdx.x;
    int e0 = blockIdx.x * EB;
    // stage ef[e0..e0+EB) -- fully contiguous float4 stream
    {
        const f32x4* src = (const f32x4*)(ef + (size_t)e0 * E_F);
        int lim = (n_edges - e0) * (E_F / 4);  // guard for ragged tail
        if (lim > EB * (E_F / 4)) lim = EB * (E_F / 4);
#pragma unroll 2
        for (int i = tid; i < lim; i += 256) {
            f32x4 v = src[i];
            int le = i >> 4;          // i*4/64
            int k = (i & 15) << 2;    // (i*4)%64
            *(f32x4*)&sef[le][k] = v;
        }
    }
    __syncthreads();
    int le = tid >> 3;
    int h = tid & 7;
    int e = e0 + le;
    if (e >= n_edges) return;
    int s = eidx[e];
    int t = eidx[n_edges + e];

    // ef @ We column h from LDS (16x ds_read_b128, conflict-free)
    float sc = be[h];
    const float* row = &sef[le][0];
#pragma unroll
    for (int k4 = 0; k4 < E_F / 4; k4++) {
        f32x4 v = *(const f32x4*)(row + k4 * 4);
        sc += v[0] * We[(k4 * 4 + 0) * NUM_H + h] + v[1] * We[(k4 * 4 + 1) * NUM_H + h] +
              v[2] * We[(k4 * 4 + 2) * NUM_H + h] + v[3] * We[(k4 * 4 + 3) * NUM_H + h];
    }

    // GATv2 score: vectorized 16B gathers of left[t], right[s] head-slices
    const short8* Lp = (const short8*)(left + (size_t)t * HD + h * DIM);
    const short8* Rp = (const short8*)(right + (size_t)s * HD + h * DIM);
    short8 l0 = Lp[0], l1 = Lp[1];
    short8 r0 = Rp[0], r1 = Rp[1];
    const float* avh = av + h * DIM;
#pragma unroll
    for (int d = 0; d < 8; d++) {
        float x = bs2f(l0[d]) + bs2f(r0[d]);
        x = x > 0.0f ? x : NEG_SLOPE * x;
        sc += x * avh[d];
    }
#pragma unroll
    for (int d = 0; d < 8; d++) {
        float x = bs2f(l1[d]) + bs2f(r1[d]);
        x = x > 0.0f ? x : NEG_SLOPE * x;
        sc += x * avh[8 + d];
    }
    es[(size_t)e * NUM_H + h] = f2b(expf(sc));
}

// ---------------- K2b: CSR permute (scatter-only, latency-tolerant) ---------
// Sequential reads (eidx, es); scattered fire-and-forget writes (srcs,
// es_csr). Tiny VGPR footprint -> near-full occupancy hides the RMW latency
// of partial-line scattered stores.
__global__ void k_perm(const int* __restrict__ eidx,
                       const __hip_bfloat16* __restrict__ es,
                       int* __restrict__ cursor, int* __restrict__ srcs,
                       __hip_bfloat16* __restrict__ es_csr, int n_edges) {
    int e = blockIdx.x * blockDim.x + threadIdx.x;
    if (e >= n_edges) return;
    int t = eidx[n_edges + e];
    int pos = atomicAdd(&cursor[t], 1);
    srcs[pos] = eidx[e];
    *(short8*)(es_csr + (size_t)pos * NUM_H) =
        *(const short8*)(es + (size_t)e * NUM_H);
}

// ---------------- K3: gather-aggregate, 1 wave/node, 4 edges in flight ------
// lane = sub*16 + c16: sub = edge-subgroup (0..3), c16 = 16B chunk of the
// 256B val row (head h = c16>>1). Each lane: short8 (16B) load -> 1KB/instr
// coalescing, 4 independent row-gathers per iteration. Butterfly over
// sub (xor 16,32) folds partial sums; lanes sub==0 write the row.
__global__ __launch_bounds__(64) void k_agg(
    const int* __restrict__ offs, const int* __restrict__ srcs,
    const __hip_bfloat16* __restrict__ es_csr,
    const __hip_bfloat16* __restrict__ val,
    float* __restrict__ nagg, int n_nodes) {
    int t = blockIdx.x;
    if (t >= n_nodes) return;
    int lane = threadIdx.x;
    int sub = lane >> 4;
    int c16 = lane & 15;
    int h = c16 >> 1;
    int beg = offs[t], end = offs[t + 1];

    float acc[8] = {0.f, 0.f, 0.f, 0.f, 0.f, 0.f, 0.f, 0.f};
    float wsum = 0.0f;
#pragma unroll 2
    for (int i0 = beg; i0 < end; i0 += 4) {
        int i = i0 + sub;
        bool act = i < end;
        int ii = act ? i : beg;                       // safe address for inactive lanes
        int s = srcs[ii];                             // sequential (broadcast x16)
        float w = b2f(es_csr[(size_t)ii * NUM_H + h]);  // sequential stream
        if (!act) w = 0.0f;
        short8 v = *(const short8*)(val + (size_t)s * HD + c16 * 8);  // 16B gather
        wsum += w;
#pragma unroll
        for (int d = 0; d < 8; d++) acc[d] += w * bs2f(v[d]);
    }
    // fold the 4 edge-subgroups (lanes differing only in sub)
#pragma unroll
    for (int m = 16; m <= 32; m <<= 1) {
        wsum += __shfl_xor(wsum, m);
#pragma unroll
        for (int d = 0; d < 8; d++) acc[d] += __shfl_xor(acc[d], m);
    }
    if (sub == 0) {
        float inv = 1.0f / (wsum + 1e-10f);
        f32x4 o0, o1;
#pragma unroll
        for (int d = 0; d < 4; d++) { o0[d] = acc[d] * inv; o1[d] = acc[4 + d] * inv; }
        float* dst = nagg + (size_t)t * HD + c16 * 8;
        *(f32x4*)dst = o0;
        *(f32x4*)(dst + 4) = o1;
    }
}

// ---------------- K4: output projection, NB nodes per block ----------------
__global__ void k_out(const float* __restrict__ nagg, const float* __restrict__ Wo,
                      const float* __restrict__ bo, float* __restrict__ out, int n_nodes) {
    __shared__ float srow[NB][HD];
    int node0 = blockIdx.x * NB;
    int j = threadIdx.x;  // 0..127
    for (int i = j; i < NB * HD; i += 128)
        srow[i / HD][i % HD] = nagg[(size_t)node0 * HD + i];
    __syncthreads();
    float a[NB];
    float b = bo[j];
#pragma unroll
    for (int n = 0; n < NB; n++) a[n] = b;
    for (int k = 0; k < HD; k++) {
        float w = Wo[k * HD + j];
#pragma unroll
        for (int n = 0; n < NB; n++) a[n] += srow[n][k] * w;
    }
#pragma unroll
    for (int n = 0; n < NB; n++) out[(size_t)(node0 + n) * HD + j] = a[n];
}

extern "C" void kernel_launch(void* const* d_in, const int* in_sizes, int n_in,
                              void* d_out, int out_size, void* d_ws, size_t ws_size,
                              hipStream_t stream) {
    const float* nf = (const float*)d_in[0];
    const int* eidx = (const int*)d_in[1];
    const float* ef = (const float*)d_in[2];
    const float* Wl = (const float*)d_in[3];
    const float* bl = (const float*)d_in[4];
    const float* Wr = (const float*)d_in[5];
    const float* br = (const float*)d_in[6];
    const float* We = (const float*)d_in[7];
    const float* be = (const float*)d_in[8];
    const float* av = (const float*)d_in[9];
    const float* Wv = (const float*)d_in[10];
    const float* bv = (const float*)d_in[11];
    const float* Wo = (const float*)d_in[12];
    const float* bo = (const float*)d_in[13];
    float* out = (float*)d_out;

    const int n_nodes = in_sizes[0] / IN_F;   // 50000
    const int n_edges = in_sizes[1] / 2;      // 800000
    const size_t NHD = (size_t)n_nodes * HD;  // 6.4M

    // workspace layout (~42.3 MB — identical footprint to verified baseline):
    //   [256B pad]
    //   left   bf16 [NHD]      12.8 MB   } nagg f32 [NHD] (25.6 MB) overlays
    //   right  bf16 [NHD]      12.8 MB   } left+right after escore+perm done
    //   es     bf16 [E*8]      12.8 MB   } edge-ordered; Whi/Wlo (384 KB)
    //                                    } overlay its start (dead pre-escore)
    //   deg    int  [N]        200 KB
    //   offs   int  [N+1]      200 KB
    //   cursor int  [N]        200 KB
    //   srcs   int  [E]        3.2 MB  (CSR-ordered source node per slot)
    // d_out (25.6 MB f32): first half = val bf16 [NHD]; second half =
    // es_csr bf16 [E*8] (12.8 MB). Both dead by the time k_out rewrites out.
    char* base = (char*)d_ws;
    __hip_bfloat16* left  = (__hip_bfloat16*)(base + 256);
    __hip_bfloat16* right = left + NHD;
    __hip_bfloat16* es    = right + NHD;
    int* deg    = (int*)(es + (size_t)n_edges * NUM_H);
    int* offs   = deg + n_nodes;
    int* cursor = offs + n_nodes + 1;
    int* srcs   = cursor + n_nodes;
    __bf16* Whi = (__bf16*)es;          // overlay (region is 12.8 MB; we use 384 KB)
    __bf16* Wlo = Whi + (size_t)WELEMS;
    float* nagg = (float*)left;
    __hip_bfloat16* val = (__hip_bfloat16*)d_out;
    __hip_bfloat16* es_csr = val + NHD;  // second half of d_out

    int eb = (n_edges + 255) / 256;  // 3125

    // weight decomposition + pack (tiny; stays L2-resident for k_projm)
    k_wprep<<<(KSTEPS * NCT * 64 + 255) / 256, 256, 0, stream>>>(Wl, Wr, Wv, Whi, Wlo);

    // CSR build (histogram + scan; permute runs after escore)
    k_zero_int<<<64, 256, 0, stream>>>(deg, n_nodes);
    k_hist<<<eb, 256, 0, stream>>>(eidx, deg, n_edges);
    k_scan<<<1, 1024, 0, stream>>>(deg, offs, cursor, n_nodes);

    // projections via MFMA (writes left/right in ws, val in d_out)
    k_projm<<<(n_nodes + 63) / 64, 256, 0, stream>>>(nf, Whi, Wlo, bl, br, bv,
                                                     left, right, val, n_nodes);

    // edge scores, edge-ordered (overwrites Whi/Wlo region with es)
    k_escore<<<(n_edges + EB - 1) / EB, 256, 0, stream>>>(
        eidx, ef, We, be, av, left, right, es, n_edges);

    // CSR permute: es -> es_csr, sources -> srcs
    k_perm<<<eb, 256, 0, stream>>>(eidx, es, cursor, srcs, es_csr, n_edges);

    // gather-aggregate + normalize (left/right dead -> nagg overlays them)
    k_agg<<<n_nodes, 64, 0, stream>>>(offs, srcs, es_csr, val, nagg, n_nodes);

    // output projection (fully rewrites d_out)
    k_out<<<n_nodes / NB, 128, 0, stream>>>(nagg, Wo, bo, out, n_nodes);
}

// Round 8
// 744.259 us; speedup vs baseline: 1.4142x; 1.0197x over previous
//
#include <hip/hip_runtime.h>
#include <hip/hip_bf16.h>
#include <stdint.h>

#define NUM_H 8
#define DIM 16
#define HD 128
#define IN_F 256
#define E_F 64
#define NEG_SLOPE 0.2f
#define NB 8  // nodes per block in k_out
#define EB 32 // edges per block in k_edot

#define NCT 24    // col-tiles: 3 matrices * 128 cols / 16
#define KSTEPS 8  // 256 / 32
#define WELEMS (KSTEPS * NCT * 64 * 8)  // 98304 bf16 elems per W plane (192 KB)

typedef __bf16 bf16x8 __attribute__((ext_vector_type(8)));
typedef float f32x4 __attribute__((ext_vector_type(4)));
typedef short short8 __attribute__((ext_vector_type(8)));

__device__ __forceinline__ float b2f(__hip_bfloat16 x) { return __bfloat162float(x); }
__device__ __forceinline__ __hip_bfloat16 f2b(float x) { return __float2bfloat16(x); }
__device__ __forceinline__ float bs2f(short s) {
    uint32_t u = ((uint32_t)(uint16_t)s) << 16;
    return __builtin_bit_cast(float, u);
}

// ---------------- zero int array (deg) ----------------
__global__ void k_zero_int(int* p, int n) {
    int i = blockIdx.x * blockDim.x + threadIdx.x;
    int stride = gridDim.x * blockDim.x;
    for (; i < n; i += stride) p[i] = 0;
}

// ---------------- CSR build: histogram of targets ----------------
__global__ void k_hist(const int* __restrict__ eidx, int* __restrict__ deg, int n_edges) {
    int e = blockIdx.x * blockDim.x + threadIdx.x;
    if (e < n_edges) atomicAdd(&deg[eidx[n_edges + e]], 1);
}

// ---------------- CSR build: exclusive scan (single block) ----------------
__global__ void k_scan(const int* __restrict__ deg, int* __restrict__ offs,
                       int* __restrict__ cursor, int n) {
    __shared__ int part[1024];
    int tid = threadIdx.x;
    int chunk = (n + 1023) / 1024;
    int base = tid * chunk;
    int hi = base + chunk < n ? base + chunk : n;
    int sum = 0;
    for (int i = base; i < hi; i++) sum += deg[i];
    part[tid] = sum;
    __syncthreads();
    for (int off = 1; off < 1024; off <<= 1) {
        int v = (tid >= off) ? part[tid - off] : 0;
        __syncthreads();
        part[tid] += v;
        __syncthreads();
    }
    int run = (tid == 0) ? 0 : part[tid - 1];  // exclusive prefix of this chunk
    for (int i = base; i < hi; i++) {
        offs[i] = run;
        cursor[i] = run;
        run += deg[i];
    }
    if (tid == 0) offs[n] = part[1023];
}

// ---------------- W prep: decompose Wl|Wr|Wv into bf16 hi/lo, fragment order --
// Fragment order: elem index = ((ks*NCT + ct)*64 + lane)*8 + i
//   k  = ks*32 + 8*(lane>>4) + i   (B operand: 8 contiguous k per lane)
//   gc = ct*16 + (lane&15)         (concat col: 0..127=Wl, 128..255=Wr, 256..383=Wv)
__global__ void k_wprep(const float* __restrict__ Wl, const float* __restrict__ Wr,
                        const float* __restrict__ Wv,
                        __bf16* __restrict__ Whi, __bf16* __restrict__ Wlo) {
    int tid = blockIdx.x * blockDim.x + threadIdx.x;
    if (tid >= KSTEPS * NCT * 64) return;
    int l = tid & 63;
    int ctks = tid >> 6;
    int ct = ctks % NCT;
    int ks = ctks / NCT;
    int gc = ct * 16 + (l & 15);
    int m = gc >> 7;
    int c = gc & 127;
    const float* W = (m == 0) ? Wl : (m == 1) ? Wr : Wv;
    bf16x8 h8, l8;
#pragma unroll
    for (int i = 0; i < 8; i++) {
        int k = ks * 32 + ((l >> 4) << 3) + i;
        float w = W[k * HD + c];
        __bf16 hi = (__bf16)w;
        __bf16 lo = (__bf16)(w - (float)hi);
        h8[i] = hi;
        l8[i] = lo;
    }
    *(bf16x8*)(Whi + (size_t)tid * 8) = h8;
    *(bf16x8*)(Wlo + (size_t)tid * 8) = l8;
}

// ---------------- K1: node projections via MFMA (split-precision bf16) -------
// Block = 4 waves; wave w owns rows [blockIdx*64 + w*16, +16), all 384 cols.
// C = A_hi@W_hi + A_lo@W_hi + A_hi@W_lo  (~fp32-accurate; lo*lo term ~2^-18)
__global__ __launch_bounds__(256, 2) void k_projm(
    const float* __restrict__ nf,
    const __bf16* __restrict__ Whi, const __bf16* __restrict__ Wlo,
    const float* __restrict__ bl, const float* __restrict__ br,
    const float* __restrict__ bv,
    __hip_bfloat16* __restrict__ left, __hip_bfloat16* __restrict__ right,
    __hip_bfloat16* __restrict__ val, int n_nodes) {
    int l = threadIdx.x & 63;
    int wave = threadIdx.x >> 6;
    int row0 = blockIdx.x * 64 + wave * 16;
    if (row0 >= n_nodes) return;  // n_nodes % 16 == 0, so wave-level guard suffices
    int lr = l & 15, lg = l >> 4;
    const float* arow = nf + (size_t)(row0 + lr) * IN_F + lg * 8;

    const f32x4 zero = {0.f, 0.f, 0.f, 0.f};
    f32x4 acc[NCT];
#pragma unroll
    for (int ct = 0; ct < NCT; ct++) acc[ct] = zero;

    for (int ks = 0; ks < KSTEPS; ks++) {
        // A fragment: row = lr, k = ks*32 + lg*8 + i  (8 contiguous floats)
        f32x4 a0 = *(const f32x4*)(arow + ks * 32);
        f32x4 a1 = *(const f32x4*)(arow + ks * 32 + 4);
        bf16x8 ah, al;
#pragma unroll
        for (int i = 0; i < 4; i++) {
            __bf16 h = (__bf16)a0[i];
            ah[i] = h;
            al[i] = (__bf16)(a0[i] - (float)h);
        }
#pragma unroll
        for (int i = 0; i < 4; i++) {
            __bf16 h = (__bf16)a1[i];
            ah[4 + i] = h;
            al[4 + i] = (__bf16)(a1[i] - (float)h);
        }
        const bf16x8* wh = (const bf16x8*)(Whi) + (size_t)ks * NCT * 64 + l;
        const bf16x8* wl = (const bf16x8*)(Wlo) + (size_t)ks * NCT * 64 + l;
#pragma unroll
        for (int ct = 0; ct < NCT; ct++) {
            bf16x8 bh = wh[ct * 64];
            bf16x8 blo = wl[ct * 64];
            acc[ct] = __builtin_amdgcn_mfma_f32_16x16x32_bf16(ah, bh, acc[ct], 0, 0, 0);
            acc[ct] = __builtin_amdgcn_mfma_f32_16x16x32_bf16(al, bh, acc[ct], 0, 0, 0);
            acc[ct] = __builtin_amdgcn_mfma_f32_16x16x32_bf16(ah, blo, acc[ct], 0, 0, 0);
        }
    }

    // Epilogue: D layout col = lr, row = lg*4 + r  (m89-verified)
#pragma unroll
    for (int ct = 0; ct < NCT; ct++) {
        const int m = ct >> 3;               // 0=left, 1=right, 2=val (compile-time)
        int c = ((ct & 7) << 4) + lr;
        float bias = (m == 0) ? bl[c] : (m == 1) ? br[c] : bv[c];
        __hip_bfloat16* dst = (m == 0) ? left : (m == 1) ? right : val;
#pragma unroll
        for (int r = 0; r < 4; r++) {
            int row = row0 + lg * 4 + r;
            dst[(size_t)row * HD + c] = f2b(acc[ct][r] + bias);
        }
    }
}

// ---------------- K2a: edge-feature dot (pure stream, no gathers) -----------
// sp[e*8+h] = be[h] + ef[e] . We[:,h]   (bf16 out; same error order as old es)
__global__ __launch_bounds__(256) void k_edot(
    const float* __restrict__ ef, const float* __restrict__ We,
    const float* __restrict__ be, __hip_bfloat16* __restrict__ sp, int n_edges) {
    __shared__ float sef[EB][68];
    int tid = threadIdx.x;
    int e0 = blockIdx.x * EB;
    {
        const f32x4* src = (const f32x4*)(ef + (size_t)e0 * E_F);
        int lim = (n_edges - e0) * (E_F / 4);  // guard for ragged tail
        if (lim > EB * (E_F / 4)) lim = EB * (E_F / 4);
#pragma unroll 2
        for (int i = tid; i < lim; i += 256) {
            f32x4 v = src[i];
            *(f32x4*)&sef[i >> 4][(i & 15) << 2] = v;
        }
    }
    __syncthreads();
    int le = tid >> 3;
    int h = tid & 7;
    int e = e0 + le;
    if (e >= n_edges) return;
    float sc = be[h];
    const float* row = &sef[le][0];
#pragma unroll
    for (int k4 = 0; k4 < E_F / 4; k4++) {
        f32x4 v = *(const f32x4*)(row + k4 * 4);
        sc += v[0] * We[(k4 * 4 + 0) * NUM_H + h] + v[1] * We[(k4 * 4 + 1) * NUM_H + h] +
              v[2] * We[(k4 * 4 + 2) * NUM_H + h] + v[3] * We[(k4 * 4 + 3) * NUM_H + h];
    }
    sp[(size_t)e * NUM_H + h] = f2b(sc);  // coalesced sequential write
}

// ---------------- K2b: gather-score-exp + CSR scatter (latency-tolerant) ----
// No LDS, low VGPR -> high occupancy hides gather + scattered-store latency.
// Per (edge, head) thread: seq reads (eidx, sp), 16B gathers of left/right
// head-slices, LeakyReLU dot, exp, atomic slot claim (h==0, shfl-broadcast),
// scatter srcs + es_csr (8 head-lanes of an edge write 16B contiguous).
__global__ __launch_bounds__(256) void k_gperm(
    const int* __restrict__ eidx, const __hip_bfloat16* __restrict__ sp,
    const __hip_bfloat16* __restrict__ left,
    const __hip_bfloat16* __restrict__ right,
    const float* __restrict__ av,
    int* __restrict__ cursor, int* __restrict__ srcs,
    __hip_bfloat16* __restrict__ es_csr, int n_edges) {
    int gid = blockIdx.x * blockDim.x + threadIdx.x;
    int e = gid >> 3;
    int h = gid & 7;
    if (e >= n_edges) return;
    int s = eidx[e];
    int t = eidx[n_edges + e];

    int lane = threadIdx.x & 63;
    int pos = 0;
    if (h == 0) pos = atomicAdd(&cursor[t], 1);
    pos = __shfl(pos, lane & ~7);

    float sc = b2f(sp[(size_t)e * NUM_H + h]);
    const short8* Lp = (const short8*)(left + (size_t)t * HD + h * DIM);
    const short8* Rp = (const short8*)(right + (size_t)s * HD + h * DIM);
    short8 l0 = Lp[0], l1 = Lp[1];
    short8 r0 = Rp[0], r1 = Rp[1];
    const float* avh = av + h * DIM;
#pragma unroll
    for (int d = 0; d < 8; d++) {
        float x = bs2f(l0[d]) + bs2f(r0[d]);
        x = x > 0.0f ? x : NEG_SLOPE * x;
        sc += x * avh[d];
    }
#pragma unroll
    for (int d = 0; d < 8; d++) {
        float x = bs2f(l1[d]) + bs2f(r1[d]);
        x = x > 0.0f ? x : NEG_SLOPE * x;
        sc += x * avh[8 + d];
    }
    if (h == 0) srcs[pos] = s;
    es_csr[(size_t)pos * NUM_H + h] = f2b(expf(sc));
}

// ---------------- K3: gather-aggregate, 1 wave/node, 4 edges in flight ------
// lane = sub*16 + c16: sub = edge-subgroup (0..3), c16 = 16B chunk of the
// 256B val row (head h = c16>>1). Each lane: short8 (16B) load -> 1KB/instr
// coalescing, 4 independent row-gathers per iteration. Butterfly over
// sub (xor 16,32) folds partial sums; lanes sub==0 write the row.
__global__ __launch_bounds__(64) void k_agg(
    const int* __restrict__ offs, const int* __restrict__ srcs,
    const __hip_bfloat16* __restrict__ es_csr,
    const __hip_bfloat16* __restrict__ val,
    float* __restrict__ nagg, int n_nodes) {
    int t = blockIdx.x;
    if (t >= n_nodes) return;
    int lane = threadIdx.x;
    int sub = lane >> 4;
    int c16 = lane & 15;
    int h = c16 >> 1;
    int beg = offs[t], end = offs[t + 1];

    float acc[8] = {0.f, 0.f, 0.f, 0.f, 0.f, 0.f, 0.f, 0.f};
    float wsum = 0.0f;
#pragma unroll 2
    for (int i0 = beg; i0 < end; i0 += 4) {
        int i = i0 + sub;
        bool act = i < end;
        int ii = act ? i : beg;                       // safe address for inactive lanes
        int s = srcs[ii];                             // sequential (broadcast x16)
        float w = b2f(es_csr[(size_t)ii * NUM_H + h]);  // sequential stream
        if (!act) w = 0.0f;
        short8 v = *(const short8*)(val + (size_t)s * HD + c16 * 8);  // 16B gather
        wsum += w;
#pragma unroll
        for (int d = 0; d < 8; d++) acc[d] += w * bs2f(v[d]);
    }
    // fold the 4 edge-subgroups (lanes differing only in sub)
#pragma unroll
    for (int m = 16; m <= 32; m <<= 1) {
        wsum += __shfl_xor(wsum, m);
#pragma unroll
        for (int d = 0; d < 8; d++) acc[d] += __shfl_xor(acc[d], m);
    }
    if (sub == 0) {
        float inv = 1.0f / (wsum + 1e-10f);
        f32x4 o0, o1;
#pragma unroll
        for (int d = 0; d < 4; d++) { o0[d] = acc[d] * inv; o1[d] = acc[4 + d] * inv; }
        float* dst = nagg + (size_t)t * HD + c16 * 8;
        *(f32x4*)dst = o0;
        *(f32x4*)(dst + 4) = o1;
    }
}

// ---------------- K4: output projection, NB nodes per block ----------------
__global__ void k_out(const float* __restrict__ nagg, const float* __restrict__ Wo,
                      const float* __restrict__ bo, float* __restrict__ out, int n_nodes) {
    __shared__ float srow[NB][HD];
    int node0 = blockIdx.x * NB;
    int j = threadIdx.x;  // 0..127
    for (int i = j; i < NB * HD; i += 128)
        srow[i / HD][i % HD] = nagg[(size_t)node0 * HD + i];
    __syncthreads();
    float a[NB];
    float b = bo[j];
#pragma unroll
    for (int n = 0; n < NB; n++) a[n] = b;
    for (int k = 0; k < HD; k++) {
        float w = Wo[k * HD + j];
#pragma unroll
        for (int n = 0; n < NB; n++) a[n] += srow[n][k] * w;
    }
#pragma unroll
    for (int n = 0; n < NB; n++) out[(size_t)(node0 + n) * HD + j] = a[n];
}

extern "C" void kernel_launch(void* const* d_in, const int* in_sizes, int n_in,
                              void* d_out, int out_size, void* d_ws, size_t ws_size,
                              hipStream_t stream) {
    const float* nf = (const float*)d_in[0];
    const int* eidx = (const int*)d_in[1];
    const float* ef = (const float*)d_in[2];
    const float* Wl = (const float*)d_in[3];
    const float* bl = (const float*)d_in[4];
    const float* Wr = (const float*)d_in[5];
    const float* br = (const float*)d_in[6];
    const float* We = (const float*)d_in[7];
    const float* be = (const float*)d_in[8];
    const float* av = (const float*)d_in[9];
    const float* Wv = (const float*)d_in[10];
    const float* bv = (const float*)d_in[11];
    const float* Wo = (const float*)d_in[12];
    const float* bo = (const float*)d_in[13];
    float* out = (float*)d_out;

    const int n_nodes = in_sizes[0] / IN_F;   // 50000
    const int n_edges = in_sizes[1] / 2;      // 800000
    const size_t NHD = (size_t)n_nodes * HD;  // 6.4M

    // workspace layout (~42.3 MB — identical footprint to verified baseline):
    //   [256B pad]
    //   left   bf16 [NHD]      12.8 MB   } nagg f32 [NHD] (25.6 MB) overlays
    //   right  bf16 [NHD]      12.8 MB   } left+right after gperm is done
    //   sp     bf16 [E*8]      12.8 MB   } edge-ordered ef@We scores;
    //                                    } Whi/Wlo (384 KB) overlay its start
    //                                    } (read by projm, dead before edot)
    //   deg    int  [N]        200 KB
    //   offs   int  [N+1]      200 KB
    //   cursor int  [N]        200 KB
    //   srcs   int  [E]        3.2 MB  (CSR-ordered source node per slot)
    // d_out (25.6 MB f32): first half = val bf16 [NHD]; second half =
    // es_csr bf16 [E*8] (12.8 MB). Both dead by the time k_out rewrites out.
    char* base = (char*)d_ws;
    __hip_bfloat16* left  = (__hip_bfloat16*)(base + 256);
    __hip_bfloat16* right = left + NHD;
    __hip_bfloat16* sp    = right + NHD;
    int* deg    = (int*)(sp + (size_t)n_edges * NUM_H);
    int* offs   = deg + n_nodes;
    int* cursor = offs + n_nodes + 1;
    int* srcs   = cursor + n_nodes;
    __bf16* Whi = (__bf16*)sp;          // overlay (region is 12.8 MB; we use 384 KB)
    __bf16* Wlo = Whi + (size_t)WELEMS;
    float* nagg = (float*)left;
    __hip_bfloat16* val = (__hip_bfloat16*)d_out;
    __hip_bfloat16* es_csr = val + NHD;  // second half of d_out

    int eb = (n_edges + 255) / 256;  // 3125

    // weight decomposition + pack (tiny; stays L2-resident for k_projm)
    k_wprep<<<(KSTEPS * NCT * 64 + 255) / 256, 256, 0, stream>>>(Wl, Wr, Wv, Whi, Wlo);

    // CSR build (histogram + scan; slot-claim happens in k_gperm)
    k_zero_int<<<64, 256, 0, stream>>>(deg, n_nodes);
    k_hist<<<eb, 256, 0, stream>>>(eidx, deg, n_edges);
    k_scan<<<1, 1024, 0, stream>>>(deg, offs, cursor, n_nodes);

    // projections via MFMA (writes left/right in ws, val in d_out)
    k_projm<<<(n_nodes + 63) / 64, 256, 0, stream>>>(nf, Whi, Wlo, bl, br, bv,
                                                     left, right, val, n_nodes);

    // edge-feature scores (pure stream; overwrites Whi/Wlo region with sp)
    k_edot<<<(n_edges + EB - 1) / EB, 256, 0, stream>>>(ef, We, be, sp, n_edges);

    // gather + finish score + exp + CSR scatter
    k_gperm<<<((size_t)n_edges * NUM_H + 255) / 256, 256, 0, stream>>>(
        eidx, sp, left, right, av, cursor, srcs, es_csr, n_edges);

    // gather-aggregate + normalize (left/right dead -> nagg overlays them)
    k_agg<<<n_nodes, 64, 0, stream>>>(offs, srcs, es_csr, val, nagg, n_nodes);

    // output projection (fully rewrites d_out)
    k_out<<<n_nodes / NB, 128, 0, stream>>>(nagg, Wo, bo, out, n_nodes);
}